// Round 3
// baseline (226.611 us; speedup 1.0000x reference)
//
#include <hip/hip_runtime.h>
#include <hip/hip_bf16.h>
#include <cstdint>
#include <cstddef>

// Problem constants (fixed shapes per reference)
#define NROWS 8192
#define DIM   1024
#define BT    256          // square tile 256x256
#define BK    64           // K depth per pipeline stage; 16 stages
#define NKT   (DIM / BK)
#define NFULL 496          // 31*32/2 strictly-lower full tiles (8 XCDs x 62)
#define NDD   16           // double-diagonal blocks (2 masked diag tiles each)
#define NBLK  (NFULL + NDD)     // 512 = exactly 2 rounds of 256 CUs
#define EPS 1e-8f
// E pre-scaled by sqrt(10*log2(e)) so MFMA accumulates 10*log2(e)*<a,b>;
// epilogue is a bare exp2f.
#define PRESCALE 3.798288f

// LDS: 2 buffers x (A 256x64 + B 256x64) bf16 = 2 x 64 KB = 128 KB
#define ABUF_E 16384       // elems per A (or B) K-tile
#define BUF_E  32768       // elems per buffer (A ++ B)

typedef short  bf16x8  __attribute__((ext_vector_type(8)));
typedef float  floatx4 __attribute__((ext_vector_type(4)));

typedef __attribute__((address_space(1))) const void CGV;
typedef __attribute__((address_space(3))) void LV;

__device__ __forceinline__ void async_load16(const void* g, void* l) {
    __builtin_amdgcn_global_load_lds((CGV*)g, (LV*)l, 16, 0, 0);
}

__device__ __forceinline__ unsigned short f2bf_rne(float f) {
    union { float f; unsigned u; } c; c.f = f;
    unsigned u = c.u;
    unsigned r = (u + 0x7fffu + ((u >> 16) & 1u)) >> 16;
    return (unsigned short)r;
}

// ---------------------------------------------------------------------------
// Kernel A: fp32 -> bf16 (RNE) with PRESCALE folded in. First 64 blocks also
// zero the 16384-float accumulator region.
// ---------------------------------------------------------------------------
__global__ __launch_bounds__(256) void convert_kernel(
    const float* __restrict__ in, unsigned short* __restrict__ out,
    float* __restrict__ accum /* all_sum ++ pos_sum, 2*NROWS floats */)
{
    int i = (blockIdx.x * 256 + threadIdx.x) * 4;
    float4 v = *(const float4*)(in + i);
    ushort4 o;
    o.x = f2bf_rne(v.x * PRESCALE);
    o.y = f2bf_rne(v.y * PRESCALE);
    o.z = f2bf_rne(v.z * PRESCALE);
    o.w = f2bf_rne(v.w * PRESCALE);
    *(ushort4*)(out + i) = o;
    if (blockIdx.x < (2 * NROWS) / 256)
        accum[blockIdx.x * 256 + threadIdx.x] = 0.0f;
}

// ---------------------------------------------------------------------------
// run_tile<DIAG>: one 256x256 tile with the 4-phase m201-style schedule.
//
// Phase split per K-tile (16 MFMA each): p0:(mt0-3,ksub0) p1:(mt0-3,ksub1)
// p2:(mt4-7,ksub0) p3:(mt4-7,ksub1).  bF[ksub] held in regs p0->p2 / p1->p3.
// A "region0" = rows {0..63,128..191} (the mt0-3 rows of both wave halves,
// bit6==0) is fully consumed after p1; region1 after p3. Each region = two
// contiguous 8KB blocks = 2 global_load_lds per thread.
// Staging (steady, tile T, nb = other buffer, bb = current):
//   p0: A-region1(T+1)->nb, B(T+1) blocks {0,64}->nb
//   p1: B(T+1) blocks {128,192}->nb
//   p2: A-region0(T+2)->bb   (region0 of bb freed at the p1->p2 barrier)
//   p3: vmcnt(2) -> barrier  (retires ALL of tile T+1's data; the 2
//       A-region0(T+2) loads ride across the barrier — never drain to 0)
// Lead: B(T+1) 2-3 phases; A-r0(T+2) 6 phases. One vmcnt per tile.
// DIAG blocks: B panel == A panel -> skip all B stages, read bF from the A
// region (same rows, same swizzle). Per-frag liveMask skips strictly-upper
// 16x16 frags (epilogue grow>gcol rule zeroes them anyway).
// Swizzle (R3/R9/R11-verified, BK=64/128B rows): LDS slot s of row r holds
// global chunk s^(r&7); staged linear-dest with pre-swizzled global source;
// read slot = ((ksub*4+quad) ^ (colw&7)).
// ---------------------------------------------------------------------------
template<bool DIAG>
__device__ __forceinline__ void run_tile(
    const unsigned short* __restrict__ E,
    const int*            __restrict__ labels,
    float*                __restrict__ all_sum,
    float*                __restrict__ pos_sum,
    unsigned short* S, int rBase, int cBase)
{
    const int tid  = threadIdx.x;
    const int lane = tid & 63;
    const int w    = tid >> 6;      // wave 0..7
    const int wm   = w >> 2;        // row half
    // col quarter; w>=4 remapped [3,2,0,1] so SIMD pairs {w,w+4} balance
    // diag live-frag counts (36/36/32/32 of 64).
    const int wn   = (w < 4) ? w : ((0x1023 >> ((w & 3) * 4)) & 0xF);
    const int colw = lane & 15;
    const int quad = lane >> 4;
    const int swz  = colw & 7;
    const int cs0  = ((0 | quad) ^ swz) << 3;   // ksub0 slot offset (elems)
    const int cs1  = ((4 | quad) ^ swz) << 3;   // ksub1

    // Stage addressing: thread covers row w*8+l8 of each 64-row block,
    // chunk gch = (lane&7)^(row&7) (pre-swizzled global source).
    const int l8  = lane >> 3;
    const int gch = (lane & 7) ^ l8;
    const unsigned short* gA = E + (size_t)(rBase + w * 8 + l8) * DIM + gch * 8;
    const unsigned short* gB = E + (size_t)(cBase + w * 8 + l8) * DIM + gch * 8;
    const int ldsT = w * 512 + lane * 8;   // lds elem offset within an 8KB block

#define STG_A(rb, T, dB) async_load16(gA + (size_t)(rb) * DIM + (T) * BK,   \
                                      &S[(dB) + (rb) * 64 + ldsT])
#define STG_B(rb, T, dB) async_load16(gB + (size_t)(rb) * DIM + (T) * BK,   \
                                      &S[(dB) + ABUF_E + (rb) * 64 + ldsT])

    unsigned liveMask = 0xFFFFFFFFu;
    if (DIAG) {
        liveMask = 0u;
        #pragma unroll
        for (int mt = 0; mt < 8; ++mt)
            #pragma unroll
            for (int nt = 0; nt < 4; ++nt)
                if (wm * 128 + mt * 16 + 15 >= wn * 64 + nt * 16)
                    liveMask |= 1u << (mt * 4 + nt);
    }

    floatx4 acc[8][4];
    #pragma unroll
    for (int i = 0; i < 8; ++i)
        #pragma unroll
        for (int j = 0; j < 4; ++j)
            acc[i][j] = (floatx4)0.0f;

    // Prologue: all of tile 0 + A-region0(1); retire tile 0, keep 2 in flight.
    STG_A(0, 0, 0);  STG_A(128, 0, 0);          // A-region0(0)
    STG_A(64, 0, 0); STG_A(192, 0, 0);          // A-region1(0)
    if (!DIAG) { STG_B(0, 0, 0); STG_B(64, 0, 0);
                 STG_B(128, 0, 0); STG_B(192, 0, 0); }  // B(0)
    STG_A(0, 1, BUF_E); STG_A(128, 1, BUF_E);   // A-region0(1)
    asm volatile("s_waitcnt vmcnt(2)" ::: "memory");
    __builtin_amdgcn_s_barrier();
    __builtin_amdgcn_sched_barrier(0);

    bf16x8 bFr[2][4];

#define PH_READB(KS, CS)                                                      \
    _Pragma("unroll")                                                         \
    for (int nt = 0; nt < 4; ++nt)                                            \
        bFr[KS][nt] = *(const bf16x8*)&S[bRegion +                            \
                          (wn * 64 + nt * 16 + colw) * BK + (CS)];

#define PH_COMPUTE(M, KS, CS)                                                 \
    {                                                                         \
        bf16x8 aF[4];                                                         \
        _Pragma("unroll")                                                     \
        for (int i = 0; i < 4; ++i)                                           \
            aF[i] = *(const bf16x8*)&S[bb +                                   \
                        (wm * 128 + ((M) * 4 + i) * 16 + colw) * BK + (CS)];  \
        __builtin_amdgcn_s_setprio(1);                                        \
        _Pragma("unroll")                                                     \
        for (int i = 0; i < 4; ++i) {                                         \
            _Pragma("unroll")                                                 \
            for (int nt = 0; nt < 4; ++nt) {                                  \
                if (!DIAG || ((liveMask >> ((((M) * 4 + i) * 4) + nt)) & 1u)) \
                    acc[(M) * 4 + i][nt] =                                    \
                        __builtin_amdgcn_mfma_f32_16x16x32_bf16(              \
                            aF[i], bFr[KS][nt], acc[(M) * 4 + i][nt], 0, 0, 0);\
            }                                                                 \
        }                                                                     \
        __builtin_amdgcn_s_setprio(0);                                        \
    }

#define BARSEQ  __builtin_amdgcn_sched_barrier(0);                            \
                __builtin_amdgcn_s_barrier();                                 \
                __builtin_amdgcn_sched_barrier(0);

    for (int kt = 0; kt < NKT; ++kt) {
        const int bb = (kt & 1) ? BUF_E : 0;
        const int nb = bb ^ BUF_E;
        const int bRegion = DIAG ? bb : (bb + ABUF_E);
        const bool s1 = (kt <= NKT - 2);
        const bool s2 = (kt <= NKT - 3);

        // ---- p0: stage A-r1(kt+1) + B(kt+1) first half; compute (mt0-3, k0)
        if (s1) {
            STG_A(64, kt + 1, nb); STG_A(192, kt + 1, nb);
            if (!DIAG) { STG_B(0, kt + 1, nb); STG_B(64, kt + 1, nb); }
        }
        PH_READB(0, cs0)
        PH_COMPUTE(0, 0, cs0)
        BARSEQ

        // ---- p1: stage B(kt+1) second half; compute (mt0-3, k1)
        if (s1 && !DIAG) { STG_B(128, kt + 1, nb); STG_B(192, kt + 1, nb); }
        PH_READB(1, cs1)
        PH_COMPUTE(0, 1, cs1)
        BARSEQ

        // ---- p2: stage A-r0(kt+2) into freed region0 of bb; compute (mt4-7, k0)
        if (s2) { STG_A(0, kt + 2, bb); STG_A(128, kt + 2, bb); }
        PH_COMPUTE(1, 0, cs0)
        BARSEQ

        // ---- p3: compute (mt4-7, k1); tile-end counted wait
        PH_COMPUTE(1, 1, cs1)
        __builtin_amdgcn_sched_barrier(0);
        if (s2) asm volatile("s_waitcnt vmcnt(2)" ::: "memory");
        else    asm volatile("s_waitcnt vmcnt(0)" ::: "memory");
        __builtin_amdgcn_s_barrier();
        __builtin_amdgcn_sched_barrier(0);
    }
#undef PH_COMPUTE
#undef PH_READB
#undef BARSEQ
#undef STG_A
#undef STG_B

    // Epilogue. C/D layout (16x16x32): col = lane&15, row = quad*4 + reg.
    // Uniform rule: element (grow, gcol) counts iff grow > gcol; contributes
    // to row grow AND col gcol (R11-verified). Dead diag frags hold 0 and
    // are masked by the same rule.
    float labc[4];
    int   gcolv[4];
    #pragma unroll
    for (int nt = 0; nt < 4; ++nt) {
        gcolv[nt] = cBase + wn * 64 + nt * 16 + colw;
        labc[nt]  = (float)labels[gcolv[nt]];
    }

    float colAll[4] = {0.f, 0.f, 0.f, 0.f};
    float colPos[4] = {0.f, 0.f, 0.f, 0.f};

    #pragma unroll
    for (int mt = 0; mt < 8; ++mt) {
        const int growBase = rBase + wm * 128 + mt * 16 + quad * 4;
        #pragma unroll
        for (int r = 0; r < 4; ++r) {
            const int grow = growBase + r;
            const float labr = (float)labels[grow];
            float sAll = 0.f, sPos = 0.f;
            #pragma unroll
            for (int nt = 0; nt < 4; ++nt) {
                float ev = exp2f(acc[mt][nt][r]);   // PRESCALE folded into E
                ev = (grow > gcolv[nt]) ? ev : 0.0f; // strictly-lower only
                sAll += ev;
                sPos += ev * labc[nt];
                colAll[nt] += ev;
                colPos[nt] += ev * labr;
            }
            // row-reduce across the 16 lanes (same quad) sharing this row
            #pragma unroll
            for (int off = 1; off < 16; off <<= 1) {
                sAll += __shfl_xor(sAll, off);
                sPos += __shfl_xor(sPos, off);
            }
            if (colw == 0 && sAll != 0.f) {
                atomicAdd(&all_sum[grow], sAll);
                atomicAdd(&pos_sum[grow], sPos);
            }
        }
    }

    // col-reduce: sum across quads (lanes differing in bits 4,5)
    #pragma unroll
    for (int nt = 0; nt < 4; ++nt) {
        float aa = colAll[nt], p = colPos[nt];
        aa += __shfl_xor(aa, 16);  p += __shfl_xor(p, 16);
        aa += __shfl_xor(aa, 32);  p += __shfl_xor(p, 32);
        if (quad == 0 && aa != 0.f) {
            atomicAdd(&all_sum[gcolv[nt]], aa);
            atomicAdd(&pos_sum[gcolv[nt]], p);
        }
    }
}

// ---------------------------------------------------------------------------
// Kernel B driver: 496 strictly-lower full tiles (XCD-chunked) + 16
// double-diagonal blocks dispatched last (each: two masked diag tiles,
// ~0.6T apiece) -> 512 blocks = 2 clean rounds, ~90% packing.
// ---------------------------------------------------------------------------
__global__ __launch_bounds__(512, 2) void gemm_fused_kernel(
    const unsigned short* __restrict__ E,
    const int*            __restrict__ labels,
    float*                __restrict__ all_sum,
    float*                __restrict__ pos_sum)
{
    __shared__ __align__(16) unsigned short S[2 * BUF_E];   // 128 KB

    const int b = blockIdx.x;
    if (b < NFULL) {
        const int t = (b & 7) * 62 + (b >> 3);      // 496 = 8 x 62, XCD-local
        int a = (int)((1.0f + sqrtf(1.0f + 8.0f * (float)t)) * 0.5f);
        while (a * (a - 1) / 2 > t) --a;
        while ((a + 1) * a / 2 <= t) ++a;
        const int c = t - a * (a - 1) / 2;          // c < a
        run_tile<false>(E, labels, all_sum, pos_sum, S, a * BT, c * BT);
    } else {
        const int i = b - NFULL;                    // 0..15 -> diag tiles 2i,2i+1
        for (int r = 0; r < 2; ++r) {
            const int d = (2 * i + r) * BT;
            run_tile<true>(E, labels, all_sum, pos_sum, S, d, d);
        }
    }
}

// ---------------------------------------------------------------------------
// Kernel C: loss = mean over rows with lab==1 of -log(pos/(all+eps)); 0 if n_ref<2
// ---------------------------------------------------------------------------
__global__ __launch_bounds__(1024) void finalize_kernel(
    const float* __restrict__ all_sum,
    const float* __restrict__ pos_sum,
    const int*   __restrict__ labels,
    float*       __restrict__ out)
{
    __shared__ float sSum[1024];
    __shared__ float sCnt[1024];
    const int tid = threadIdx.x;
    float lsum = 0.f, lcnt = 0.f;
    for (int i = tid; i < NROWS; i += 1024) {
        if (labels[i] > 0) {
            float p = pos_sum[i];
            float a = all_sum[i] + EPS;
            lsum += -logf(p / a);
            lcnt += 1.0f;
        }
    }
    sSum[tid] = lsum;
    sCnt[tid] = lcnt;
    __syncthreads();
    for (int s = 512; s > 0; s >>= 1) {
        if (tid < s) { sSum[tid] += sSum[tid + s]; sCnt[tid] += sCnt[tid + s]; }
        __syncthreads();
    }
    if (tid == 0) {
        float n = sCnt[0];
        out[0] = (n < 2.0f) ? 0.0f : sSum[0] / fmaxf(n, 1.0f);
    }
}

// ---------------------------------------------------------------------------
extern "C" void kernel_launch(void* const* d_in, const int* in_sizes, int n_in,
                              void* d_out, int out_size, void* d_ws, size_t ws_size,
                              hipStream_t stream) {
    const float* emb    = (const float*)d_in[0];
    const int*   labels = (const int*)d_in[1];
    float*       out    = (float*)d_out;

    // workspace layout: [bf16 E: 16 MB][all_sum: 32 KB][pos_sum: 32 KB]
    unsigned short* Ebf = (unsigned short*)d_ws;
    const size_t embBytes = (size_t)NROWS * DIM * sizeof(unsigned short);
    float* all_sum = (float*)((char*)d_ws + embBytes);
    float* pos_sum = all_sum + NROWS;

    convert_kernel<<<(NROWS * DIM) / (4 * 256), 256, 0, stream>>>(emb, Ebf, all_sum);

    gemm_fused_kernel<<<NBLK, 512, 0, stream>>>(Ebf, labels, all_sum, pos_sum);

    finalize_kernel<<<1, 1024, 0, stream>>>(all_sum, pos_sum, labels, out);
}